// Round 1
// baseline (137.602 us; speedup 1.0000x reference)
//
#include <hip/hip_runtime.h>
#include <math.h>

#define A_TOT     8192
#define KANCH     128
#define NUM_MODS  6
#define NPRED     30
#define AG_PER_BLK 4

// One wave (64 lanes) per agent; 4 agents per 256-thread block.
__global__ __launch_bounds__(256) void goals_main(
    const float* __restrict__ pred_goals,   // (A,K,5)
    const float* __restrict__ anchor_ctrs,  // (A,K,2)
    const float* __restrict__ gt_preds,     // (A,30,2)
    const int*   __restrict__ has_preds,    // (A,30)  bool as int32
    const int*   __restrict__ interest,     // (A)     bool as int32
    float* __restrict__ out_goals,          // (A,2)  = d_out + 2
    float* __restrict__ ws_cls,             // (A)
    float* __restrict__ ws_reg)             // (A)
{
    __shared__ float lg[AG_PER_BLK][KANCH];
    __shared__ float px[AG_PER_BLK][KANCH];
    __shared__ float py[AG_PER_BLK][KANCH];
    __shared__ int   ord[AG_PER_BLK][KANCH];
    __shared__ unsigned char sel[AG_PER_BLK][KANCH];

    const int wave = threadIdx.x >> 6;
    const int lane = threadIdx.x & 63;
    const int a = blockIdx.x * AG_PER_BLK + wave;
    if (a >= A_TOT) return;

    // ---- load phase: logits + pred_xy into LDS (2 items/lane) ----
    #pragma unroll
    for (int it = 0; it < 2; ++it) {
        const int k = lane + 64 * it;
        const float* g  = pred_goals  + ((size_t)(a * KANCH + k)) * 5;
        const float* ac = anchor_ctrs + ((size_t)(a * KANCH + k)) * 2;
        float g0 = g[0], g1 = g[1], g2 = g[2];
        float ax = ac[0], ay = ac[1];
        lg[wave][k] = g0;
        px[wave][k] = ax + g1;
        py[wave][k] = ay + g2;
        sel[wave][k] = 0;
    }
    __syncthreads();

    // ---- rank sort: stable argsort of -logits (desc, ties by index asc) ----
    #pragma unroll
    for (int it = 0; it < 2; ++it) {
        const int k = lane + 64 * it;
        const float mv = lg[wave][k];
        int rank = 0;
        for (int j = 0; j < KANCH; ++j) {
            const float vj = lg[wave][j];          // LDS broadcast read
            rank += (vj > mv) || (vj == mv && j < k);
        }
        ord[wave][rank] = k;                       // scatter: unique ranks
    }
    __syncthreads();

    if (lane != 0) return;

    // ---- greedy NMS on lane 0; early-exit at 6 selected ----
    float sx[NUM_MODS], sy[NUM_MODS];
    int   top[NUM_MODS];
    int   cnt = 0;
    for (int j = 0; j < KANCH; ++j) {
        const int id = ord[wave][j];
        const float xj = px[wave][id], yj = py[wave][id];
        bool ok = true;
        for (int m = 0; m < cnt; ++m) {
            const float dx = xj - sx[m], dy = yj - sy[m];
            if (dx * dx + dy * dy < 4.0f) { ok = false; break; }  // d < NMS_THR
        }
        if (ok) {
            sx[cnt] = xj; sy[cnt] = yj; top[cnt] = id; ++cnt;
            sel[wave][j] = 1;
            if (cnt == NUM_MODS) break;   // top[:6] fully determined
        }
    }
    if (cnt < NUM_MODS) {                 // fill from unselected, sorted order
        for (int j = 0; j < KANCH && cnt < NUM_MODS; ++j) {
            if (!sel[wave][j]) {
                const int id = ord[wave][j];
                sx[cnt] = px[wave][id]; sy[cnt] = py[wave][id];
                top[cnt] = id; ++cnt;
            }
        }
    }

    // ---- last valid gt index: last j with has_preds true, else 29 ----
    const int* hp = has_preds + a * NPRED;
    int last = -1;
    for (int j = 0; j < NPRED; ++j)
        if (hp[j] != 0) last = j;
    int hlast = 1;
    if (last < 0) { last = NPRED - 1; hlast = 0; }

    const float gx = gt_preds[((size_t)(a * NPRED + last)) * 2 + 0];
    const float gy = gt_preds[((size_t)(a * NPRED + last)) * 2 + 1];
    const float w  = (interest[a] != 0) ? 1.0f : 0.0f;

    // ---- cls (softplus sum - selected logit), argmin mode ----
    float best = INFINITY;
    int   bm = 0;
    float splus = 0.0f;
    #pragma unroll
    for (int m = 0; m < NUM_MODS; ++m) {
        const float lo = lg[wave][top[m]];
        splus += fmaxf(lo, 0.0f) + log1pf(expf(-fabsf(lo)));  // logaddexp(x,0)
        const float dx = sx[m] - gx, dy = sy[m] - gy;
        const float dist = sqrtf(dx * dx + dy * dy);
        if (dist < best) { best = dist; bm = m; }              // first-min tie
    }
    const float cls = w * (splus - lg[wave][top[bm]]);

    // ---- smooth-L1 reg loss + goals output ----
    const float pgx = sx[bm], pgy = sy[bm];
    const float dxx = pgx - gx, dyy = pgy - gy;
    const float axx = fabsf(dxx), ayy = fabsf(dyy);
    const float sl1 = (axx < 1.0f ? 0.5f * dxx * dxx : axx - 0.5f)
                    + (ayy < 1.0f ? 0.5f * dyy * dyy : ayy - 0.5f);
    const float rw = w * (float)hlast;

    ws_cls[a] = cls;
    ws_reg[a] = rw * sl1;
    out_goals[2 * a + 0] = (rw > 0.0f) ? pgx : 0.0f;
    out_goals[2 * a + 1] = (rw > 0.0f) ? pgy : 0.0f;
}

// Single-block reduction of the per-agent partials into the two scalars.
__global__ __launch_bounds__(256) void goals_reduce(
    const float* __restrict__ ws_cls,
    const float* __restrict__ ws_reg,
    float* __restrict__ out)
{
    __shared__ float scls[256];
    __shared__ float sreg[256];
    const int t = threadIdx.x;
    float c = 0.0f, r = 0.0f;
    for (int i = t; i < A_TOT; i += 256) {
        c += ws_cls[i];
        r += ws_reg[i];
    }
    scls[t] = c; sreg[t] = r;
    __syncthreads();
    for (int s = 128; s > 0; s >>= 1) {
        if (t < s) { scls[t] += scls[t + s]; sreg[t] += sreg[t + s]; }
        __syncthreads();
    }
    if (t == 0) { out[0] = scls[0]; out[1] = sreg[0]; }
}

extern "C" void kernel_launch(void* const* d_in, const int* in_sizes, int n_in,
                              void* d_out, int out_size, void* d_ws, size_t ws_size,
                              hipStream_t stream) {
    const float* pred_goals  = (const float*)d_in[0];
    const float* anchor_ctrs = (const float*)d_in[1];
    // d_in[2] anchor_dirs, d_in[3] agt_ctrs, d_in[4] agt_feats, d_in[5] agt_vels:
    // dead code in the reference (feed only the unused _pred_trajs) — not read.
    const float* gt_preds    = (const float*)d_in[6];
    const int*   has_preds   = (const int*)d_in[7];
    const int*   interest    = (const int*)d_in[8];

    float* out       = (float*)d_out;
    float* out_goals = out + 2;
    float* ws_cls    = (float*)d_ws;
    float* ws_reg    = ws_cls + A_TOT;

    const int grid = A_TOT / AG_PER_BLK;   // 2048 blocks x 256 threads
    goals_main<<<grid, 256, 0, stream>>>(pred_goals, anchor_ctrs, gt_preds,
                                         has_preds, interest,
                                         out_goals, ws_cls, ws_reg);
    goals_reduce<<<1, 256, 0, stream>>>(ws_cls, ws_reg, out);
}

// Round 2
// 110.480 us; speedup vs baseline: 1.2455x; 1.2455x over previous
//
#include <hip/hip_runtime.h>
#include <math.h>

#define A_TOT      8192
#define KANCH      128
#define NUM_MODS   6
#define NPRED      30
#define AG_PER_BLK 4
#define NBLK       (A_TOT / AG_PER_BLK)   // 2048

// One wave (64 lanes) per agent; 4 agents per 256-thread block.
// NMS is done as 6 wave-parallel argmax+deactivate rounds, all in registers.
__global__ __launch_bounds__(256) void goals_main(
    const float* __restrict__ pred_goals,   // (A,K,5)
    const float* __restrict__ anchor_ctrs,  // (A,K,2)
    const float* __restrict__ gt_preds,     // (A,30,2)
    const int*   __restrict__ has_preds,    // (A,30)  bool as int32
    const int*   __restrict__ interest,     // (A)     bool as int32
    float* __restrict__ out_goals,          // (A,2)  = d_out + 2
    float* __restrict__ part_cls,           // (NBLK)
    float* __restrict__ part_reg)           // (NBLK)
{
    __shared__ float sc[AG_PER_BLK], sr[AG_PER_BLK];

    const int wave = threadIdx.x >> 6;
    const int lane = threadIdx.x & 63;
    const int a = blockIdx.x * AG_PER_BLK + wave;

    // ---- per-lane candidates: k0 = lane, k1 = lane+64 ----
    const size_t b0 = (size_t)a * KANCH + lane;
    const size_t b1 = b0 + 64;
    const float* g0 = pred_goals + b0 * 5;
    const float* g1 = pred_goals + b1 * 5;
    float lg0 = g0[0], x0 = g0[1], y0 = g0[2];
    float lg1 = g1[0], x1 = g1[1], y1 = g1[2];
    const float2 ac0 = ((const float2*)anchor_ctrs)[b0];
    const float2 ac1 = ((const float2*)anchor_ctrs)[b1];
    x0 += ac0.x; y0 += ac0.y;
    x1 += ac1.x; y1 += ac1.y;

    // Orderable u64 key: (monotone-float-bits << 8) | (255 - k).
    // Max key == max logit, ties -> smaller k (matches stable argsort).
    auto mkkey = [](float lg, int k) -> unsigned long long {
        unsigned ub = __float_as_uint(lg);
        unsigned ou = (ub & 0x80000000u) ? ~ub : (ub | 0x80000000u);
        return ((unsigned long long)ou << 8) | (unsigned long long)(255 - k);
    };
    const unsigned long long key0 = mkkey(lg0, lane);
    const unsigned long long key1 = mkkey(lg1, lane + 64);
    bool alive0 = true, alive1 = true;   // not selected and not NMS-rejected
    bool avail0 = true, avail1 = true;   // not selected (fill pool)

    // ---- last valid gt index via ballot ----
    const int* hp = has_preds + (size_t)a * NPRED;
    bool h = (lane < NPRED) ? (hp[lane] != 0) : false;
    unsigned long long hmask = __ballot(h);
    int last; float hlast;
    if (hmask) { last = 63 - __builtin_clzll(hmask); hlast = 1.0f; }
    else       { last = NPRED - 1;                   hlast = 0.0f; }
    const float gx = gt_preds[((size_t)a * NPRED + last) * 2 + 0];
    const float gy = gt_preds[((size_t)a * NPRED + last) * 2 + 1];
    const float w  = (interest[a] != 0) ? 1.0f : 0.0f;

    // ---- 6 rounds of argmax + deactivate ----
    float splus = 0.0f;
    float bestd = INFINITY, selx = 0.0f, sely = 0.0f, sellg = 0.0f;
    #pragma unroll
    for (int m = 0; m < NUM_MODS; ++m) {
        unsigned long long k0 = alive0 ? key0 : 0ull;
        unsigned long long k1 = alive1 ? key1 : 0ull;
        unsigned long long key = k0 > k1 ? k0 : k1;
        #pragma unroll
        for (int off = 1; off < 64; off <<= 1) {
            unsigned long long o = __shfl_xor(key, off);
            if (o > key) key = o;
        }
        const bool fill = (key == 0ull);   // wave-uniform
        if (fill) {                        // no alive left: take best unselected
            k0 = avail0 ? key0 : 0ull;
            k1 = avail1 ? key1 : 0ull;
            key = k0 > k1 ? k0 : k1;
            #pragma unroll
            for (int off = 1; off < 64; off <<= 1) {
                unsigned long long o = __shfl_xor(key, off);
                if (o > key) key = o;
            }
        }
        const int kw    = 255 - (int)(key & 0xffull);
        const unsigned ou = (unsigned)(key >> 8);
        const unsigned ub = (ou & 0x80000000u) ? (ou ^ 0x80000000u) : ~ou;
        const float blg = __uint_as_float(ub);
        const int owner = kw & 63;
        const int slot  = kw >> 6;         // uniform
        const float bx = __shfl(slot ? x1 : x0, owner);
        const float by = __shfl(slot ? y1 : y0, owner);
        if (lane == owner) { if (slot) avail1 = false; else avail0 = false; }
        if (!fill) {
            const float dx0 = x0 - bx, dy0 = y0 - by;
            if (dx0 * dx0 + dy0 * dy0 < 4.0f) alive0 = false;  // d < NMS_THR
            const float dx1 = x1 - bx, dy1 = y1 - by;
            if (dx1 * dx1 + dy1 * dy1 < 4.0f) alive1 = false;
        }
        // accumulate mode outputs (uniform across lanes)
        splus += fmaxf(blg, 0.0f) + log1pf(expf(-fabsf(blg)));  // softplus
        const float ddx = bx - gx, ddy = by - gy;
        const float dist = sqrtf(ddx * ddx + ddy * ddy);
        if (dist < bestd) { bestd = dist; selx = bx; sely = by; sellg = blg; }
    }

    // ---- losses (uniform values; lane 0 stores) ----
    const float cls = w * (splus - sellg);
    const float dxx = selx - gx, dyy = sely - gy;
    const float axx = fabsf(dxx), ayy = fabsf(dyy);
    const float sl1 = (axx < 1.0f ? 0.5f * dxx * dxx : axx - 0.5f)
                    + (ayy < 1.0f ? 0.5f * dyy * dyy : ayy - 0.5f);
    const float rw = w * hlast;

    if (lane == 0) {
        sc[wave] = cls;
        sr[wave] = rw * sl1;
        out_goals[2 * (size_t)a + 0] = (rw > 0.0f) ? selx : 0.0f;
        out_goals[2 * (size_t)a + 1] = (rw > 0.0f) ? sely : 0.0f;
    }
    __syncthreads();
    if (threadIdx.x == 0) {
        part_cls[blockIdx.x] = sc[0] + sc[1] + sc[2] + sc[3];
        part_reg[blockIdx.x] = sr[0] + sr[1] + sr[2] + sr[3];
    }
}

// Reduce 2048 block partials into the two scalars. One block.
__global__ __launch_bounds__(256) void goals_reduce(
    const float* __restrict__ part_cls,
    const float* __restrict__ part_reg,
    float* __restrict__ out)
{
    __shared__ float scls[4], sreg[4];
    const int t = threadIdx.x;
    const int lane = t & 63, wave = t >> 6;
    float c = 0.0f, r = 0.0f;
    #pragma unroll
    for (int i = 0; i < NBLK / 256; ++i) {
        c += part_cls[t + 256 * i];
        r += part_reg[t + 256 * i];
    }
    #pragma unroll
    for (int off = 1; off < 64; off <<= 1) {
        c += __shfl_xor(c, off);
        r += __shfl_xor(r, off);
    }
    if (lane == 0) { scls[wave] = c; sreg[wave] = r; }
    __syncthreads();
    if (t == 0) {
        out[0] = scls[0] + scls[1] + scls[2] + scls[3];
        out[1] = sreg[0] + sreg[1] + sreg[2] + sreg[3];
    }
}

extern "C" void kernel_launch(void* const* d_in, const int* in_sizes, int n_in,
                              void* d_out, int out_size, void* d_ws, size_t ws_size,
                              hipStream_t stream) {
    const float* pred_goals  = (const float*)d_in[0];
    const float* anchor_ctrs = (const float*)d_in[1];
    // d_in[2..5] (anchor_dirs, agt_ctrs, agt_feats, agt_vels) are dead code in
    // the reference (feed only the unused _pred_trajs) — not read.
    const float* gt_preds    = (const float*)d_in[6];
    const int*   has_preds   = (const int*)d_in[7];
    const int*   interest    = (const int*)d_in[8];

    float* out       = (float*)d_out;
    float* out_goals = out + 2;
    float* part_cls  = (float*)d_ws;
    float* part_reg  = part_cls + NBLK;

    goals_main<<<NBLK, 256, 0, stream>>>(pred_goals, anchor_ctrs, gt_preds,
                                         has_preds, interest,
                                         out_goals, part_cls, part_reg);
    goals_reduce<<<1, 256, 0, stream>>>(part_cls, part_reg, out);
}

// Round 3
// 99.312 us; speedup vs baseline: 1.3856x; 1.1125x over previous
//
#include <hip/hip_runtime.h>
#include <math.h>

#define A_TOT      8192
#define KANCH      128
#define NUM_MODS   6
#define NPRED      30
#define AG_PER_BLK 4
#define NBLK       (A_TOT / AG_PER_BLK)   // 2048

// One wave (64 lanes) per agent; 4 agents per 256-thread block.
// NMS = 6 rounds of wave-parallel argmax (32-bit butterfly + ballot owner
// resolve) + register deactivate. No LDS in the hot path.
__global__ __launch_bounds__(256) void goals_main(
    const float* __restrict__ pred_goals,   // (A,K,5)
    const float* __restrict__ anchor_ctrs,  // (A,K,2)
    const float* __restrict__ gt_preds,     // (A,30,2)
    const int*   __restrict__ has_preds,    // (A,30)  bool as int32
    const int*   __restrict__ interest,     // (A)     bool as int32
    float* __restrict__ out_goals,          // (A,2)  = d_out + 2
    float* __restrict__ part_cls,           // (NBLK)
    float* __restrict__ part_reg)           // (NBLK)
{
    __shared__ float sc[AG_PER_BLK], sr[AG_PER_BLK];

    const int wave = threadIdx.x >> 6;
    const int lane = threadIdx.x & 63;
    const int a = blockIdx.x * AG_PER_BLK + wave;

    // ---- per-lane candidates: k0 = lane, k1 = lane+64 ----
    const size_t b0 = (size_t)a * KANCH + lane;
    const size_t b1 = b0 + 64;
    const float* g0 = pred_goals + b0 * 5;
    const float* g1 = pred_goals + b1 * 5;
    const float lg0 = g0[0];
    float x0 = g0[1], y0 = g0[2];
    const float lg1 = g1[0];
    float x1 = g1[1], y1 = g1[2];
    const float2 ac0 = ((const float2*)anchor_ctrs)[b0];
    const float2 ac1 = ((const float2*)anchor_ctrs)[b1];
    x0 += ac0.x; y0 += ac0.y;
    x1 += ac1.x; y1 += ac1.y;

    // Monotone-orderable bits: max over these == max logit.
    auto okey = [](float lg) -> unsigned {
        unsigned ub = __float_as_uint(lg);
        return (ub & 0x80000000u) ? ~ub : (ub | 0x80000000u);
    };
    const unsigned okey0 = okey(lg0);
    const unsigned okey1 = okey(lg1);
    bool alive0 = true, alive1 = true;   // not selected and not NMS-rejected
    bool avail0 = true, avail1 = true;   // not selected (fill pool)

    // ---- last valid gt index via ballot ----
    const int* hp = has_preds + (size_t)a * NPRED;
    const bool h = (lane < NPRED) ? (hp[lane] != 0) : false;
    const unsigned long long hmask = __ballot(h);
    int last; float hlast;
    if (hmask) { last = 63 - __builtin_clzll(hmask); hlast = 1.0f; }
    else       { last = NPRED - 1;                   hlast = 0.0f; }
    const float gx = gt_preds[((size_t)a * NPRED + last) * 2 + 0];
    const float gy = gt_preds[((size_t)a * NPRED + last) * 2 + 1];
    const float w  = (interest[a] != 0) ? 1.0f : 0.0f;

    // ---- 6 rounds of argmax + deactivate ----
    float splus = 0.0f;
    float bestd2 = INFINITY, selx = 0.0f, sely = 0.0f, sellg = 0.0f;
    #pragma unroll
    for (int m = 0; m < NUM_MODS; ++m) {
        unsigned key = max(alive0 ? okey0 : 0u, alive1 ? okey1 : 0u);
        #pragma unroll
        for (int off = 1; off < 64; off <<= 1) {
            const unsigned o = __shfl_xor(key, off);
            key = key > o ? key : o;
        }
        const bool fill = (key == 0u);   // wave-uniform: no alive candidates
        if (fill) {                      // take best not-yet-selected instead
            key = max(avail0 ? okey0 : 0u, avail1 ? okey1 : 0u);
            #pragma unroll
            for (int off = 1; off < 64; off <<= 1) {
                const unsigned o = __shfl_xor(key, off);
                key = key > o ? key : o;
            }
        }
        // Owner resolve: slot-0 pool first (k<64 beats k>=64 on logit ties),
        // lowest lane = lowest k. Matches the reference's stable argsort.
        const bool e0 = (fill ? avail0 : alive0) && (okey0 == key);
        const bool e1 = (fill ? avail1 : alive1) && (okey1 == key);
        const unsigned long long m0 = __ballot(e0);
        const unsigned long long m1 = __ballot(e1);
        int owner, slot;
        if (m0) { owner = __builtin_ctzll(m0); slot = 0; }
        else    { owner = __builtin_ctzll(m1); slot = 1; }
        const float bx = __shfl(slot ? x1 : x0, owner);
        const float by = __shfl(slot ? y1 : y0, owner);
        if (lane == owner) {
            if (slot) { avail1 = false; alive1 = false; }
            else      { avail0 = false; alive0 = false; }
        }
        if (!fill) {
            const float dx0 = x0 - bx, dy0 = y0 - by;
            if (dx0 * dx0 + dy0 * dy0 < 4.0f) alive0 = false;  // d < NMS_THR
            const float dx1 = x1 - bx, dy1 = y1 - by;
            if (dx1 * dx1 + dy1 * dy1 < 4.0f) alive1 = false;
        }
        // decode winner logit from the monotone bits (uniform)
        const unsigned ub = (key & 0x80000000u) ? (key ^ 0x80000000u) : ~key;
        const float blg = __uint_as_float(ub);
        // softplus via fast exp/log (threshold is ~5e3; error ~1e-6 rel)
        splus += fmaxf(blg, 0.0f) + __logf(1.0f + __expf(-fabsf(blg)));
        const float ddx = bx - gx, ddy = by - gy;
        const float d2 = ddx * ddx + ddy * ddy;   // argmin(sqrt) == argmin(sq)
        if (d2 < bestd2) { bestd2 = d2; selx = bx; sely = by; sellg = blg; }
    }

    // ---- losses (uniform values; lane 0 stores) ----
    const float cls = w * (splus - sellg);
    const float dxx = selx - gx, dyy = sely - gy;
    const float axx = fabsf(dxx), ayy = fabsf(dyy);
    const float sl1 = (axx < 1.0f ? 0.5f * dxx * dxx : axx - 0.5f)
                    + (ayy < 1.0f ? 0.5f * dyy * dyy : ayy - 0.5f);
    const float rw = w * hlast;

    if (lane == 0) {
        sc[wave] = cls;
        sr[wave] = rw * sl1;
        out_goals[2 * (size_t)a + 0] = (rw > 0.0f) ? selx : 0.0f;
        out_goals[2 * (size_t)a + 1] = (rw > 0.0f) ? sely : 0.0f;
    }
    __syncthreads();
    if (threadIdx.x == 0) {
        part_cls[blockIdx.x] = sc[0] + sc[1] + sc[2] + sc[3];
        part_reg[blockIdx.x] = sr[0] + sr[1] + sr[2] + sr[3];
    }
}

// Reduce 2048 block partials into the two scalars. One block.
__global__ __launch_bounds__(256) void goals_reduce(
    const float* __restrict__ part_cls,
    const float* __restrict__ part_reg,
    float* __restrict__ out)
{
    __shared__ float scls[4], sreg[4];
    const int t = threadIdx.x;
    const int lane = t & 63, wv = t >> 6;
    float c = 0.0f, r = 0.0f;
    #pragma unroll
    for (int i = 0; i < NBLK / 256; ++i) {
        c += part_cls[t + 256 * i];
        r += part_reg[t + 256 * i];
    }
    #pragma unroll
    for (int off = 1; off < 64; off <<= 1) {
        c += __shfl_xor(c, off);
        r += __shfl_xor(r, off);
    }
    if (lane == 0) { scls[wv] = c; sreg[wv] = r; }
    __syncthreads();
    if (t == 0) {
        out[0] = scls[0] + scls[1] + scls[2] + scls[3];
        out[1] = sreg[0] + sreg[1] + sreg[2] + sreg[3];
    }
}

extern "C" void kernel_launch(void* const* d_in, const int* in_sizes, int n_in,
                              void* d_out, int out_size, void* d_ws, size_t ws_size,
                              hipStream_t stream) {
    const float* pred_goals  = (const float*)d_in[0];
    const float* anchor_ctrs = (const float*)d_in[1];
    // d_in[2..5] (anchor_dirs, agt_ctrs, agt_feats, agt_vels) are dead code in
    // the reference (feed only the unused _pred_trajs) — not read.
    const float* gt_preds    = (const float*)d_in[6];
    const int*   has_preds   = (const int*)d_in[7];
    const int*   interest    = (const int*)d_in[8];

    float* out       = (float*)d_out;
    float* out_goals = out + 2;
    float* part_cls  = (float*)d_ws;
    float* part_reg  = part_cls + NBLK;

    goals_main<<<NBLK, 256, 0, stream>>>(pred_goals, anchor_ctrs, gt_preds,
                                         has_preds, interest,
                                         out_goals, part_cls, part_reg);
    goals_reduce<<<1, 256, 0, stream>>>(part_cls, part_reg, out);
}